// Round 1
// baseline (53049.945 us; speedup 1.0000x reference)
//
#include <hip/hip_runtime.h>
#include <math.h>

// Problem dims
#define B_DIM 4
#define N_DIM 2048
#define K_DIM 30
#define VO    16
#define SO    100
#define VIN   17
#define SM    132
#define HV_DIM (3*VO + SO)   // 148
#define HM_DIM (3*VIN + SM)  // 183
#define EV_DIM (3*(VO+VIN) + SO + SM) // 331
#define NT 256

struct Params {
    const float* h_V;
    const float* h_M;
    const int*   mask_V;
    const int*   mask_attend;
    // w[0..3]=wev1 (wh,ws,bs,wv), w[4..7]=wev2, w[8..11]=wev3,
    // w[12..15]=wdh1, w[16..19]=wdh2, w[20]=ln1_g, w[21]=ln1_b, w[22]=ln2_g, w[23]=ln2_b
    const float* w[24];
    float*       out;
};

// Generic GVP on LDS buffers. in: [3*nv_in vectors (c-major)][ns_in scalars]
// out: [3*nv_out][ns_out]. vh/vn are LDS scratch. All threads must enter.
__device__ inline void gvp_block(const float* __restrict__ in, float* __restrict__ out,
                                 float* __restrict__ vh, float* __restrict__ vn,
                                 int nv_in, int ns_in, int H, int ns_out, int nv_out,
                                 const float* __restrict__ wh, const float* __restrict__ ws,
                                 const float* __restrict__ bs, const float* __restrict__ wv,
                                 bool act, int tid)
{
    // vh[c*H + h] = sum_i v[c,i] * wh[i,h]
    for (int idx = tid; idx < 3*H; idx += NT) {
        int c = idx / H, h = idx - c*H;
        const float* vrow = in + c*nv_in;
        float acc = 0.f;
        for (int i = 0; i < nv_in; ++i) acc = fmaf(vrow[i], wh[i*H + h], acc);
        vh[idx] = acc;
    }
    __syncthreads();
    // vn[h] = ||vh[:,h]||
    for (int h = tid; h < H; h += NT) {
        float a = vh[h], b = vh[H + h], c = vh[2*H + h];
        vn[h] = sqrtf(fmaxf(a*a + b*b + c*c, 1e-8f));
    }
    __syncthreads();
    // s_out[j] = [s, vn] @ ws[:, j] + bs[j]  (relu if act)
    const float* sin_ = in + 3*nv_in;
    for (int j = tid; j < ns_out; j += NT) {
        float acc = bs[j];
        const float* wcol = ws + j;
        for (int i = 0; i < ns_in; ++i) acc = fmaf(sin_[i], wcol[(size_t)i * ns_out], acc);
        for (int i = 0; i < H;     ++i) acc = fmaf(vn[i],   wcol[(size_t)(ns_in + i) * ns_out], acc);
        if (act) acc = fmaxf(acc, 0.f);
        out[3*nv_out + j] = acc;
    }
    // v_out[c,o] = sum_h vh[c,h] * wv[h,o]   (disjoint LDS region, same sync window)
    for (int idx = tid; idx < 3*nv_out; idx += NT) {
        int c = idx / nv_out, o = idx - c*nv_out;
        float acc = 0.f;
        for (int h = 0; h < H; ++h) acc = fmaf(vh[c*H + h], wv[h*nv_out + o], acc);
        out[idx] = acc;
    }
    __syncthreads();
    if (act) {
        // gate: v_out *= sigmoid(||v_out[:,o]||)
        for (int o = tid; o < nv_out; o += NT) {
            float a = out[o], b = out[nv_out + o], c = out[2*nv_out + o];
            float n = sqrtf(fmaxf(a*a + b*b + c*c, 1e-8f));
            float g = 1.f / (1.f + expf(-n));
            out[o] = a*g; out[nv_out + o] = b*g; out[2*nv_out + o] = c*g;
        }
        __syncthreads();
    }
}

// GVP LayerNorm in place on x[148]: vectors / RMS(channel norms); scalars LN(eps=1e-3)
__device__ inline void gvp_ln(float* __restrict__ x,
                              const float* __restrict__ gamma, const float* __restrict__ beta,
                              float* __restrict__ red, int tid)
{
    __syncthreads();
    if (tid == 0) {
        float m = 0.f;
        for (int i = 0; i < VO; ++i) {
            float a = x[i], b = x[VO + i], c = x[2*VO + i];
            m += fmaxf(a*a + b*b + c*c, 1e-8f);
        }
        red[0] = 1.f / sqrtf(m / VO);
        float mu = 0.f;
        for (int j = 0; j < SO; ++j) mu += x[3*VO + j];
        mu /= SO;
        float var = 0.f;
        for (int j = 0; j < SO; ++j) { float d = x[3*VO + j] - mu; var += d*d; }
        var /= SO;
        red[1] = mu;
        red[2] = 1.f / sqrtf(var + 1e-3f);
    }
    __syncthreads();
    float inv = red[0], mu = red[1], isd = red[2];
    for (int i = tid; i < 3*VO; i += NT) x[i] *= inv;
    for (int j = tid; j < SO; j += NT)
        x[3*VO + j] = (x[3*VO + j] - mu) * isd * gamma[j] + beta[j];
    __syncthreads();
}

__global__ __launch_bounds__(NT) void mpnn_kernel(Params p)
{
    __shared__ float bufA[496];   // max stage width: wdh1 out = 3*32 + 400 = 496
    __shared__ float bufB[496];
    __shared__ float vh[99];      // max 3*33
    __shared__ float vn[33];
    __shared__ float dh[HV_DIM];
    __shared__ float hvbuf[HV_DIM];
    __shared__ float red[4];

    const int node = blockIdx.x;            // b*N + n
    const int tid  = threadIdx.x;
    const float* __restrict__ hv_node = p.h_V + (size_t)node * HV_DIM;

    for (int i = tid; i < HV_DIM; i += NT) dh[i] = 0.f;
    __syncthreads();

    // ---- edge loop: m = GVP3(GVP2(GVP1(h_EV))), accumulate masked sum ----
    for (int k = 0; k < K_DIM; ++k) {
        const float* __restrict__ hm = p.h_M + ((size_t)node * K_DIM + k) * HM_DIM;
        // build h_EV[331]: vectors [3,33] = concat(h_V vec [3,16], h_M vec [3,17]); scalars 100+132
        for (int i = tid; i < EV_DIM; i += NT) {
            float val;
            if (i < 99) {
                int c = i / 33, j = i - c*33;
                val = (j < VO) ? hv_node[c*VO + j] : hm[c*VIN + (j - VO)];
            } else {
                int j = i - 99;
                val = (j < SO) ? hv_node[3*VO + j] : hm[3*VIN + (j - SO)];
            }
            bufA[i] = val;
        }
        __syncthreads();
        gvp_block(bufA, bufB, vh, vn, 33, 232, 33, 100, 16,
                  p.w[0], p.w[1], p.w[2], p.w[3], true, tid);
        gvp_block(bufB, bufA, vh, vn, 16, 100, 16, 100, 16,
                  p.w[4], p.w[5], p.w[6], p.w[7], true, tid);
        gvp_block(bufA, bufB, vh, vn, 16, 100, 16, 100, 16,
                  p.w[8], p.w[9], p.w[10], p.w[11], false, tid);
        float ma = (float)p.mask_attend[(size_t)node * K_DIM + k];
        for (int i = tid; i < HV_DIM; i += NT) dh[i] += ma * bufB[i];
        __syncthreads();
    }

    // ---- hv = LN1(h_V + mean_k m) ----
    const float invK = 1.0f / (float)K_DIM;
    for (int i = tid; i < HV_DIM; i += NT) hvbuf[i] = hv_node[i] + dh[i] * invK;
    gvp_ln(hvbuf, p.w[20], p.w[21], red, tid);

    // ---- dh = W_dh(hv): GVP(16->32,100->400,act) then GVP(32->16,400->100,no act) ----
    for (int i = tid; i < HV_DIM; i += NT) bufA[i] = hvbuf[i];
    __syncthreads();
    gvp_block(bufA, bufB, vh, vn, 16, 100, 32, 400, 32,
              p.w[12], p.w[13], p.w[14], p.w[15], true, tid);
    gvp_block(bufB, bufA, vh, vn, 32, 400, 32, 100, 16,
              p.w[16], p.w[17], p.w[18], p.w[19], false, tid);

    // ---- hv = LN2(hv + dh); out = mask_V * hv ----
    for (int i = tid; i < HV_DIM; i += NT) bufA[i] += hvbuf[i];
    gvp_ln(bufA, p.w[22], p.w[23], red, tid);

    float mv = (float)p.mask_V[node];
    float* __restrict__ o = p.out + (size_t)node * HV_DIM;
    for (int i = tid; i < HV_DIM; i += NT) o[i] = mv * bufA[i];
}

extern "C" void kernel_launch(void* const* d_in, const int* in_sizes, int n_in,
                              void* d_out, int out_size, void* d_ws, size_t ws_size,
                              hipStream_t stream)
{
    Params p;
    p.h_V         = (const float*)d_in[0];
    p.h_M         = (const float*)d_in[1];
    p.mask_V      = (const int*)d_in[2];
    p.mask_attend = (const int*)d_in[3];
    for (int i = 0; i < 24; ++i) p.w[i] = (const float*)d_in[4 + i];
    p.out = (float*)d_out;

    dim3 grid(B_DIM * N_DIM);
    dim3 block(NT);
    mpnn_kernel<<<grid, block, 0, stream>>>(p);
}

// Round 3
// 2223.604 us; speedup vs baseline: 23.8576x; 23.8576x over previous
//
#include <hip/hip_runtime.h>
#include <math.h>

#define NT 256

struct P28 {
    const float *h_V, *h_M;
    const int *mask_V, *mask_attend;
    const float *w1h,*w1s,*b1,*w1v;
    const float *w2h,*w2s,*b2,*w2v;
    const float *w3h,*w3s,*b3,*w3v;
    const float *d1h,*d1s,*db1,*d1v;
    const float *d2h,*d2s,*db2,*d2v;
    const float *g1,*be1,*g2,*be2;
    float *out, *dh;
};

// ---------------------------------------------------------------------------
// Tiled GEMM on LDS A-operand, global B streamed through LDS chunks.
// out[j*MP + m] = relu?( bias[j] + sum_{k<uniK} uni[k]*B[k][j]
//                        + sum_{ka<KA} A(ka)[m]*B[uniK+ka][j] )
//   A rows: ka < split -> A0 + ka*MP ; else A1 + (ka-split)*MP
//   B element [k][j] = Bg[k*ldB + j]  (caller may column-slice via Bg/ldB).
// One thread computes a 4(edge)x4(col) tile in 16 scalar registers.
// Requires (MP/4)*((N+3)/4) <= NT. All NT threads must call (coop staging).
// Final __syncthreads() precedes stores, so outL may alias A0/A1.
// ---------------------------------------------------------------------------
__device__ void gemm(const float* A0, int split, const float* A1, int KA,
                     const float* uni, int uniK,
                     const float* Bg, int ldB, int N,
                     const float* bias, bool relu,
                     float* outL, int MP, float* Bbuf, int tid)
{
    const int BBF = 1600;
    const int Npad = (N + 3) & ~3;
    const int EQ = MP >> 2;
    const int npairs = EQ * (Npad >> 2);
    const int Ktot = uniK + KA;
    int KC = BBF / Npad;
    if (KC > Ktot) KC = Ktot;

    const bool active = tid < npairs;
    const int e0 = (active ? (tid % EQ) : 0) * 4;
    const int j0 = (active ? (tid / EQ) : 0) * 4;

    float c00=0.f,c01=0.f,c02=0.f,c03=0.f;   // col j0+0, edges e0..e0+3
    float c10=0.f,c11=0.f,c12=0.f,c13=0.f;
    float c20=0.f,c21=0.f,c22=0.f,c23=0.f;
    float c30=0.f,c31=0.f,c32=0.f,c33=0.f;
    float su0=0.f,su1=0.f,su2=0.f,su3=0.f;

    for (int k0 = 0; k0 < Ktot; k0 += KC) {
        int kc = Ktot - k0; if (kc > KC) kc = KC;
        __syncthreads();
        for (int idx = tid; idx < kc * Npad; idx += NT) {
            int k = idx / Npad, j = idx - k * Npad;
            Bbuf[idx] = (j < N) ? Bg[(size_t)(k0 + k) * ldB + j] : 0.f;
        }
        __syncthreads();
        if (active) {
            for (int k = 0; k < kc; ++k) {
                int kg = k0 + k;
                float4 b4 = *(const float4*)(Bbuf + k * Npad + j0);
                if (kg < uniK) {
                    float u = uni[kg];
                    su0 = fmaf(u, b4.x, su0); su1 = fmaf(u, b4.y, su1);
                    su2 = fmaf(u, b4.z, su2); su3 = fmaf(u, b4.w, su3);
                } else {
                    int ka = kg - uniK;
                    const float* arow = (ka < split) ? (A0 + (size_t)ka * MP + e0)
                                                     : (A1 + (size_t)(ka - split) * MP + e0);
                    float4 a4 = *(const float4*)arow;
                    c00 = fmaf(a4.x, b4.x, c00); c01 = fmaf(a4.y, b4.x, c01);
                    c02 = fmaf(a4.z, b4.x, c02); c03 = fmaf(a4.w, b4.x, c03);
                    c10 = fmaf(a4.x, b4.y, c10); c11 = fmaf(a4.y, b4.y, c11);
                    c12 = fmaf(a4.z, b4.y, c12); c13 = fmaf(a4.w, b4.y, c13);
                    c20 = fmaf(a4.x, b4.z, c20); c21 = fmaf(a4.y, b4.z, c21);
                    c22 = fmaf(a4.z, b4.z, c22); c23 = fmaf(a4.w, b4.z, c23);
                    c30 = fmaf(a4.x, b4.w, c30); c31 = fmaf(a4.y, b4.w, c31);
                    c32 = fmaf(a4.z, b4.w, c32); c33 = fmaf(a4.w, b4.w, c33);
                }
            }
        }
    }
    __syncthreads();    // all A/B reads done -> stores may alias A
    if (active) {
        float4 o;
        if (j0 + 0 < N) {
            float s = su0 + (bias ? bias[j0 + 0] : 0.f);
            o.x = c00 + s; o.y = c01 + s; o.z = c02 + s; o.w = c03 + s;
            if (relu) { o.x = fmaxf(o.x,0.f); o.y = fmaxf(o.y,0.f); o.z = fmaxf(o.z,0.f); o.w = fmaxf(o.w,0.f); }
            *(float4*)(outL + (size_t)(j0 + 0) * MP + e0) = o;
        }
        if (j0 + 1 < N) {
            float s = su1 + (bias ? bias[j0 + 1] : 0.f);
            o.x = c10 + s; o.y = c11 + s; o.z = c12 + s; o.w = c13 + s;
            if (relu) { o.x = fmaxf(o.x,0.f); o.y = fmaxf(o.y,0.f); o.z = fmaxf(o.z,0.f); o.w = fmaxf(o.w,0.f); }
            *(float4*)(outL + (size_t)(j0 + 1) * MP + e0) = o;
        }
        if (j0 + 2 < N) {
            float s = su2 + (bias ? bias[j0 + 2] : 0.f);
            o.x = c20 + s; o.y = c21 + s; o.z = c22 + s; o.w = c23 + s;
            if (relu) { o.x = fmaxf(o.x,0.f); o.y = fmaxf(o.y,0.f); o.z = fmaxf(o.z,0.f); o.w = fmaxf(o.w,0.f); }
            *(float4*)(outL + (size_t)(j0 + 2) * MP + e0) = o;
        }
        if (j0 + 3 < N) {
            float s = su3 + (bias ? bias[j0 + 3] : 0.f);
            o.x = c30 + s; o.y = c31 + s; o.z = c32 + s; o.w = c33 + s;
            if (relu) { o.x = fmaxf(o.x,0.f); o.y = fmaxf(o.y,0.f); o.z = fmaxf(o.z,0.f); o.w = fmaxf(o.w,0.f); }
            *(float4*)(outL + (size_t)(j0 + 3) * MP + e0) = o;
        }
    }
}

// vn[h][e] = sqrt(max(sum_c vh[h][c*cs+e]^2, 1e-8)); vh rows of width MP
__device__ void vn_dev(const float* vh, int nch, int MP, int cs,
                       float* out, int ostr, int tid)
{
    for (int idx = tid; idx < nch * cs; idx += NT) {
        int h = idx / cs, e = idx - h * cs;
        float a = vh[h * MP + e], b = vh[h * MP + cs + e], c = vh[h * MP + 2 * cs + e];
        out[h * ostr + e] = sqrtf(fmaxf(a * a + b * b + c * c, 1e-8f));
    }
}

// in-place sigmoid-norm gate on v[o][c*cs+e], rows of width MP
__device__ void gate_dev(float* vb, int nch, int MP, int cs, int tid)
{
    for (int idx = tid; idx < nch * cs; idx += NT) {
        int o = idx / cs, e = idx - o * cs;
        float* b = vb + o * MP + e;
        float a = b[0], b1 = b[cs], c = b[2 * cs];
        float n = sqrtf(fmaxf(a * a + b1 * b1 + c * c, 1e-8f));
        float g = 1.f / (1.f + expf(-n));
        b[0] = a * g; b[cs] = b1 * g; b[2 * cs] = c * g;
    }
}

// ---------------------------------------------------------------------------
// Edge kernel: one block per node; 30 edges (+2 zero pad) as GEMM M dimension.
// ---------------------------------------------------------------------------
__global__ __launch_bounds__(NT) void edge_kernel(P28 p)
{
    __shared__ __align__(16) float Bbuf[1600];      //  6.4 KB weight chunks
    __shared__ __align__(16) float AM[165 * 32];    // 21.1 KB hM scalars(132)+vn1(33); later S2
    __shared__ __align__(16) float vhb[33 * 96];    // 12.7 KB vh / v ping-pong ([h][c*32+e])
    __shared__ __align__(16) float S1v[116 * 32];   // 14.8 KB vbuf alias -> sout1+vn2 -> sout3
    __shared__ __align__(16) float hVs[100];
    __shared__ float maskf[32];

    const int node = blockIdx.x;
    const int tid = threadIdx.x;
    const float* hV = p.h_V + (size_t)node * 148;
    float* vbuf = S1v;      // 33*96 = 3168 <= 3712
    float* S2 = AM;         // 116*32 = 3712 <= 5280

    for (int i = tid; i < 100; i += NT) hVs[i] = hV[48 + i];
    for (int i = tid; i < 32; i += NT)
        maskf[i] = (i < 30) ? (float)p.mask_attend[(size_t)node * 30 + i] : 0.f;
    // vbuf rows: i<16 = h_V vectors (replicated over e), i in [16,33) = h_M vectors
    for (int idx = tid; idx < 33 * 96; idx += NT) {
        int i = idx / 96, r = idx - i * 96, c = r >> 5, e = r & 31;
        float v = 0.f;
        if (i < 16) v = hV[c * 16 + i];
        else if (e < 30) v = p.h_M[((size_t)node * 30 + e) * 183 + c * 17 + (i - 16)];
        vbuf[idx] = v;
    }
    // AM rows 0..131: h_M scalars transposed [k][e]
    for (int idx = tid; idx < 132 * 32; idx += NT) {
        int k = idx >> 5, e = idx & 31;
        AM[idx] = (e < 30) ? p.h_M[((size_t)node * 30 + e) * 183 + 51 + k] : 0.f;
    }
    __syncthreads();

    // ---- GVP1 ----
    gemm(vbuf, 33, nullptr, 33, nullptr, 0, p.w1h, 33, 33, nullptr, false, vhb, 96, Bbuf, tid);
    __syncthreads();
    vn_dev(vhb, 33, 96, 32, AM + 132 * 32, 32, tid);                    // vn1 -> AM rows 132..164
    __syncthreads();
    gemm(AM, 165, nullptr, 165, hVs, 100, p.w1s, 100, 100, p.b1, true, S1v, 32, Bbuf, tid);
    gemm(vhb, 33, nullptr, 33, nullptr, 0, p.w1v, 16, 16, nullptr, false, vhb, 96, Bbuf, tid);
    __syncthreads();
    gate_dev(vhb, 16, 96, 32, tid);
    __syncthreads();

    // ---- GVP2 ----
    gemm(vhb, 16, nullptr, 16, nullptr, 0, p.w2h, 16, 16, nullptr, false, vhb + 16 * 96, 96, Bbuf, tid);
    __syncthreads();
    vn_dev(vhb + 16 * 96, 16, 96, 32, S1v + 100 * 32, 32, tid);         // vn2 -> S1 rows 100..115
    __syncthreads();
    gemm(S1v, 116, nullptr, 116, nullptr, 0, p.w2s, 100, 100, p.b2, true, S2, 32, Bbuf, tid);
    gemm(vhb + 16 * 96, 16, nullptr, 16, nullptr, 0, p.w2v, 16, 16, nullptr, false, vhb, 96, Bbuf, tid);
    __syncthreads();
    gate_dev(vhb, 16, 96, 32, tid);
    __syncthreads();

    // ---- GVP3 (no act) ----
    gemm(vhb, 16, nullptr, 16, nullptr, 0, p.w3h, 16, 16, nullptr, false, vhb + 16 * 96, 96, Bbuf, tid);
    __syncthreads();
    vn_dev(vhb + 16 * 96, 16, 96, 32, S2 + 100 * 32, 32, tid);          // vn3 -> S2 rows 100..115
    __syncthreads();
    gemm(S2, 116, nullptr, 116, nullptr, 0, p.w3s, 100, 100, p.b3, false, S1v, 32, Bbuf, tid);
    gemm(vhb + 16 * 96, 16, nullptr, 16, nullptr, 0, p.w3v, 16, 16, nullptr, false, vhb, 96, Bbuf, tid);
    __syncthreads();

    // ---- masked mean over 30 edges -> dh (staged in d_out) ----
    float* dhn = p.dh + (size_t)node * 148;
    for (int f = tid; f < 148; f += NT) {
        float s = 0.f;
        int e = f % 30;     // skew start to avoid bank-conflict lockstep
        if (f < 48) {
            int c = f >> 4, o = f & 15;
            const float* src = vhb + o * 96 + c * 32;
            for (int t = 0; t < 30; ++t) { s += maskf[e] * src[e]; if (++e == 30) e = 0; }
        } else {
            const float* src = S1v + (f - 48) * 32;
            for (int t = 0; t < 30; ++t) { s += maskf[e] * src[e]; if (++e == 30) e = 0; }
        }
        dhn[f] = s * (1.f / 30.f);
    }
}

// ---------------------------------------------------------------------------
// Node kernel: 16 nodes per block. LN1 -> W_dh (2 GVPs) -> LN2 -> mask.
// Reads dh from d_out (its own nodes only), then overwrites with final output.
// ---------------------------------------------------------------------------
__global__ __launch_bounds__(NT) void node_kernel(P28 p)
{
    __shared__ __align__(16) float Bbuf[1600];
    __shared__ __align__(16) float S1n[132 * 16];   // LN1 scalars (0..99) + vn (100..131)
    __shared__ __align__(16) float A2n[400 * 16];   // sout1 (relu'd)
    __shared__ __align__(16) float s2n[100 * 16];   // sout2
    __shared__ __align__(16) float hvv[16 * 48];    // LN1 vectors [i][c*16+n]
    __shared__ __align__(16) float vhA[32 * 48];
    __shared__ __align__(16) float vhB[32 * 48];
    __shared__ float mu[16], isd[16], vrm[16], mkv[16];

    const int nb = blockIdx.x * 16;
    const int tid = threadIdx.x;

    // stage x = h_V + dh
    for (int idx = tid; idx < 1600; idx += NT) {
        int n = idx & 15, j = idx >> 4;
        size_t g = (size_t)(nb + n) * 148 + 48 + j;
        S1n[idx] = p.h_V[g] + p.dh[g];
    }
    for (int idx = tid; idx < 768; idx += NT) {
        int i = idx / 48, r = idx - i * 48, c = r >> 4, n = r & 15;
        size_t g = (size_t)(nb + n) * 148 + c * 16 + i;
        hvv[idx] = p.h_V[g] + p.dh[g];
    }
    for (int i = tid; i < 16; i += NT) mkv[i] = (float)p.mask_V[nb + i];
    __syncthreads();

    // LN1 stats (one thread per node)
    if (tid < 16) {
        int n = tid;
        float sm = 0.f;
        for (int j = 0; j < 100; ++j) sm += S1n[j * 16 + n];
        float m = sm * 0.01f, var = 0.f;
        for (int j = 0; j < 100; ++j) { float d = S1n[j * 16 + n] - m; var += d * d; }
        mu[n] = m; isd[n] = rsqrtf(var * 0.01f + 1e-3f);
        float vm = 0.f;
        for (int i = 0; i < 16; ++i) {
            float a = hvv[i * 48 + n], b = hvv[i * 48 + 16 + n], c = hvv[i * 48 + 32 + n];
            vm += fmaxf(a * a + b * b + c * c, 1e-8f);
        }
        vrm[n] = rsqrtf(vm * (1.f / 16.f));
    }
    __syncthreads();
    for (int idx = tid; idx < 1600; idx += NT) {
        int n = idx & 15, j = idx >> 4;
        S1n[idx] = (S1n[idx] - mu[n]) * isd[n] * p.g1[j] + p.be1[j];
    }
    for (int idx = tid; idx < 768; idx += NT) hvv[idx] *= vrm[idx & 15];
    __syncthreads();

    // ---- W_dh GVP1: 16v->32v, 132s->400s (act) ----
    gemm(hvv, 16, nullptr, 16, nullptr, 0, p.d1h, 32, 32, nullptr, false, vhA, 48, Bbuf, tid);
    __syncthreads();
    vn_dev(vhA, 32, 48, 16, S1n + 100 * 16, 16, tid);                   // vn1 -> S1n rows 100..131
    __syncthreads();
    gemm(S1n, 132, nullptr, 132, nullptr, 0, p.d1s,       400, 200, p.db1,       true, A2n,            16, Bbuf, tid);
    gemm(S1n, 132, nullptr, 132, nullptr, 0, p.d1s + 200, 400, 200, p.db1 + 200, true, A2n + 200 * 16, 16, Bbuf, tid);
    gemm(vhA, 32, nullptr, 32, nullptr, 0, p.d1v, 32, 32, nullptr, false, vhB, 48, Bbuf, tid);
    __syncthreads();
    gate_dev(vhB, 32, 48, 16, tid);
    __syncthreads();

    // ---- W_dh GVP2: 32v->16v, 432s->100s (no act) ----
    gemm(vhB, 32, nullptr, 32, nullptr, 0, p.d2h, 32, 32, nullptr, false, vhA, 48, Bbuf, tid);
    __syncthreads();
    vn_dev(vhA, 32, 48, 16, S1n + 100 * 16, 16, tid);                   // vn2 overwrites rows 100..131
    __syncthreads();
    gemm(A2n, 400, S1n + 100 * 16, 432, nullptr, 0, p.d2s, 100, 100, p.db2, false, s2n, 16, Bbuf, tid);
    gemm(vhA, 32, nullptr, 32, nullptr, 0, p.d2v, 16, 16, nullptr, false, vhB, 48, Bbuf, tid);
    __syncthreads();

    // residual: x2 = hv + dh2
    for (int idx = tid; idx < 1600; idx += NT) s2n[idx] += S1n[idx];
    for (int idx = tid; idx < 768; idx += NT) vhB[idx] += hvv[idx];
    __syncthreads();

    // LN2 stats
    if (tid < 16) {
        int n = tid;
        float sm = 0.f;
        for (int j = 0; j < 100; ++j) sm += s2n[j * 16 + n];
        float m = sm * 0.01f, var = 0.f;
        for (int j = 0; j < 100; ++j) { float d = s2n[j * 16 + n] - m; var += d * d; }
        mu[n] = m; isd[n] = rsqrtf(var * 0.01f + 1e-3f);
        float vm = 0.f;
        for (int i = 0; i < 16; ++i) {
            float a = vhB[i * 48 + n], b = vhB[i * 48 + 16 + n], c = vhB[i * 48 + 32 + n];
            vm += fmaxf(a * a + b * b + c * c, 1e-8f);
        }
        vrm[n] = rsqrtf(vm * (1.f / 16.f));
    }
    __syncthreads();
    for (int idx = tid; idx < 1600; idx += NT) {
        int n = idx & 15, j = idx >> 4;
        s2n[idx] = (s2n[idx] - mu[n]) * isd[n] * p.g2[j] + p.be2[j];
    }
    for (int idx = tid; idx < 768; idx += NT) vhB[idx] *= vrm[idx & 15];
    __syncthreads();

    // write out = mask_V * hv2 (coalesced over f)
    for (int idx = tid; idx < 16 * 148; idx += NT) {
        int n = idx / 148, f = idx - n * 148;
        float v;
        if (f < 48) { int c = f >> 4, o = f & 15; v = vhB[o * 48 + c * 16 + n]; }
        else        { v = s2n[(f - 48) * 16 + n]; }
        p.out[(size_t)(nb + n) * 148 + f] = mkv[n] * v;
    }
}

extern "C" void kernel_launch(void* const* d_in, const int* in_sizes, int n_in,
                              void* d_out, int out_size, void* d_ws, size_t ws_size,
                              hipStream_t stream)
{
    P28 p;
    p.h_V = (const float*)d_in[0];
    p.h_M = (const float*)d_in[1];
    p.mask_V = (const int*)d_in[2];
    p.mask_attend = (const int*)d_in[3];
    const float** w = (const float**)&p.w1h;
    for (int i = 0; i < 24; ++i) w[i] = (const float*)d_in[4 + i];
    p.out = (float*)d_out;
    p.dh  = (float*)d_out;   // stage dh in d_out; node kernel reads then overwrites

    edge_kernel<<<dim3(8192), dim3(NT), 0, stream>>>(p);
    node_kernel<<<dim3(512),  dim3(NT), 0, stream>>>(p);
}

// Round 4
// 1082.958 us; speedup vs baseline: 48.9862x; 2.0533x over previous
//
#include <hip/hip_runtime.h>
#include <math.h>

#define NT 256
#define BBF 3200   // Bbuf floats (12.8 KB)

struct P28 {
    const float *h_V, *h_M;
    const int *mask_V, *mask_attend;
    const float *w1h,*w1s,*b1,*w1v;
    const float *w2h,*w2s,*b2,*w2v;
    const float *w3h,*w3s,*b3,*w3v;
    const float *d1h,*d1s,*db1,*d1v;
    const float *d2h,*d2s,*db2,*d2v;
    const float *g1,*be1,*g2,*be2;
    float *out, *dh;
};

// ---------------------------------------------------------------------------
// Tiled GEMM on LDS A-operand, global B streamed through LDS chunks with
// float4 register-prefetch pipelining (loads for chunk i+1 in flight during
// chunk i's math).
// out[j*MP + m] = relu?( bias[j] + sum_{k<uniK} uni[k]*B[k][j]
//                        + sum_{ka<KA} A(ka)[m]*B[uniK+ka][j] )
//   A rows: ka < split -> A0 + ka*MP ; else A1 + (ka-split)*MP
//   B element [k][j] = Bg[k*ldB + j]  (caller may column-slice via Bg/ldB).
// One thread computes a 4(edge)x4(col) tile in 16 scalar registers.
// Requires (MP/4)*((N+3)/4) <= NT. All NT threads must call (coop staging).
// Final __syncthreads() precedes stores, so outL may alias A0/A1.
// ---------------------------------------------------------------------------
__device__ void gemm(const float* A0, int split, const float* A1, int KA,
                     const float* uni, int uniK,
                     const float* Bg, int ldB, int N,
                     const float* bias, bool relu,
                     float* outL, int MP, float* Bbuf, int tid)
{
    const bool vec = ((N & 3) == 0) && ((ldB & 3) == 0);
    const int Npad = vec ? N : ((N + 3) & ~3);
    const int EQ = MP >> 2;
    const int npairs = EQ * (Npad >> 2);
    const int Ktot = uniK + KA;
    int KC = BBF / Npad;
    if (KC > Ktot) KC = Ktot;

    const bool active = tid < npairs;
    const int e0 = (active ? (tid % EQ) : 0) * 4;
    const int j0 = (active ? (tid / EQ) : 0) * 4;

    float c00=0.f,c01=0.f,c02=0.f,c03=0.f;
    float c10=0.f,c11=0.f,c12=0.f,c13=0.f;
    float c20=0.f,c21=0.f,c22=0.f,c23=0.f;
    float c30=0.f,c31=0.f,c32=0.f,c33=0.f;
    float su0=0.f,su1=0.f,su2=0.f,su3=0.f;

    float4 r0, r1, r2, r3;
    r0.x=r0.y=r0.z=r0.w=0.f; r1=r0; r2=r0; r3=r0;

    if (vec) {
        // prefetch chunk 0
        int kc0 = (KC < Ktot) ? KC : Ktot;
        int nf4 = (kc0 * N) >> 2;
        {
            int f4 = tid;
            if (f4 < nf4) { int f = f4*4; int k = f / N; r0 = *(const float4*)(Bg + (size_t)k*ldB + (f - k*N)); }
            f4 = tid + NT;
            if (f4 < nf4) { int f = f4*4; int k = f / N; r1 = *(const float4*)(Bg + (size_t)k*ldB + (f - k*N)); }
            f4 = tid + 2*NT;
            if (f4 < nf4) { int f = f4*4; int k = f / N; r2 = *(const float4*)(Bg + (size_t)k*ldB + (f - k*N)); }
            f4 = tid + 3*NT;
            if (f4 < nf4) { int f = f4*4; int k = f / N; r3 = *(const float4*)(Bg + (size_t)k*ldB + (f - k*N)); }
        }
    }

    for (int k0 = 0; k0 < Ktot; k0 += KC) {
        int kc = Ktot - k0; if (kc > KC) kc = KC;
        __syncthreads();            // Bbuf free (prev chunk's math done)
        if (vec) {
            int nf4 = (kc * N) >> 2;
            float4* Bb4 = (float4*)Bbuf;
            if (tid        < nf4) Bb4[tid]        = r0;
            if (tid +   NT < nf4) Bb4[tid +   NT] = r1;
            if (tid + 2*NT < nf4) Bb4[tid + 2*NT] = r2;
            if (tid + 3*NT < nf4) Bb4[tid + 3*NT] = r3;
            // prefetch next chunk
            int k0n = k0 + KC;
            if (k0n < Ktot) {
                int kcn = Ktot - k0n; if (kcn > KC) kcn = KC;
                int nf4n = (kcn * N) >> 2;
                const float* Bn = Bg + (size_t)k0n * ldB;
                int f4 = tid;
                if (f4 < nf4n) { int f = f4*4; int k = f / N; r0 = *(const float4*)(Bn + (size_t)k*ldB + (f - k*N)); }
                f4 = tid + NT;
                if (f4 < nf4n) { int f = f4*4; int k = f / N; r1 = *(const float4*)(Bn + (size_t)k*ldB + (f - k*N)); }
                f4 = tid + 2*NT;
                if (f4 < nf4n) { int f = f4*4; int k = f / N; r2 = *(const float4*)(Bn + (size_t)k*ldB + (f - k*N)); }
                f4 = tid + 3*NT;
                if (f4 < nf4n) { int f = f4*4; int k = f / N; r3 = *(const float4*)(Bn + (size_t)k*ldB + (f - k*N)); }
            }
        } else {
            for (int idx = tid; idx < kc * Npad; idx += NT) {
                int k = idx / Npad, j = idx - k * Npad;
                Bbuf[idx] = (j < N) ? Bg[(size_t)(k0 + k) * ldB + j] : 0.f;
            }
        }
        __syncthreads();            // Bbuf ready
        if (active) {
            for (int k = 0; k < kc; ++k) {
                int kg = k0 + k;
                float4 b4 = *(const float4*)(Bbuf + k * Npad + j0);
                if (kg < uniK) {
                    float u = uni[kg];
                    su0 = fmaf(u, b4.x, su0); su1 = fmaf(u, b4.y, su1);
                    su2 = fmaf(u, b4.z, su2); su3 = fmaf(u, b4.w, su3);
                } else {
                    int ka = kg - uniK;
                    const float* arow = (ka < split) ? (A0 + (size_t)ka * MP + e0)
                                                     : (A1 + (size_t)(ka - split) * MP + e0);
                    float4 a4 = *(const float4*)arow;
                    c00 = fmaf(a4.x, b4.x, c00); c01 = fmaf(a4.y, b4.x, c01);
                    c02 = fmaf(a4.z, b4.x, c02); c03 = fmaf(a4.w, b4.x, c03);
                    c10 = fmaf(a4.x, b4.y, c10); c11 = fmaf(a4.y, b4.y, c11);
                    c12 = fmaf(a4.z, b4.y, c12); c13 = fmaf(a4.w, b4.y, c13);
                    c20 = fmaf(a4.x, b4.z, c20); c21 = fmaf(a4.y, b4.z, c21);
                    c22 = fmaf(a4.z, b4.z, c22); c23 = fmaf(a4.w, b4.z, c23);
                    c30 = fmaf(a4.x, b4.w, c30); c31 = fmaf(a4.y, b4.w, c31);
                    c32 = fmaf(a4.z, b4.w, c32); c33 = fmaf(a4.w, b4.w, c33);
                }
            }
        }
    }
    __syncthreads();    // all A/B reads done -> stores may alias A
    if (active) {
        float4 o;
        if (j0 + 0 < N) {
            float s = su0 + (bias ? bias[j0 + 0] : 0.f);
            o.x = c00 + s; o.y = c01 + s; o.z = c02 + s; o.w = c03 + s;
            if (relu) { o.x = fmaxf(o.x,0.f); o.y = fmaxf(o.y,0.f); o.z = fmaxf(o.z,0.f); o.w = fmaxf(o.w,0.f); }
            *(float4*)(outL + (size_t)(j0 + 0) * MP + e0) = o;
        }
        if (j0 + 1 < N) {
            float s = su1 + (bias ? bias[j0 + 1] : 0.f);
            o.x = c10 + s; o.y = c11 + s; o.z = c12 + s; o.w = c13 + s;
            if (relu) { o.x = fmaxf(o.x,0.f); o.y = fmaxf(o.y,0.f); o.z = fmaxf(o.z,0.f); o.w = fmaxf(o.w,0.f); }
            *(float4*)(outL + (size_t)(j0 + 1) * MP + e0) = o;
        }
        if (j0 + 2 < N) {
            float s = su2 + (bias ? bias[j0 + 2] : 0.f);
            o.x = c20 + s; o.y = c21 + s; o.z = c22 + s; o.w = c23 + s;
            if (relu) { o.x = fmaxf(o.x,0.f); o.y = fmaxf(o.y,0.f); o.z = fmaxf(o.z,0.f); o.w = fmaxf(o.w,0.f); }
            *(float4*)(outL + (size_t)(j0 + 2) * MP + e0) = o;
        }
        if (j0 + 3 < N) {
            float s = su3 + (bias ? bias[j0 + 3] : 0.f);
            o.x = c30 + s; o.y = c31 + s; o.z = c32 + s; o.w = c33 + s;
            if (relu) { o.x = fmaxf(o.x,0.f); o.y = fmaxf(o.y,0.f); o.z = fmaxf(o.z,0.f); o.w = fmaxf(o.w,0.f); }
            *(float4*)(outL + (size_t)(j0 + 3) * MP + e0) = o;
        }
    }
}

// vn[h][e] = sqrt(max(sum_c vh[h][c*cs+e]^2, 1e-8)); vh rows of width MP
__device__ void vn_dev(const float* vh, int nch, int MP, int cs,
                       float* out, int ostr, int tid)
{
    for (int idx = tid; idx < nch * cs; idx += NT) {
        int h = idx / cs, e = idx - h * cs;
        float a = vh[h * MP + e], b = vh[h * MP + cs + e], c = vh[h * MP + 2 * cs + e];
        out[h * ostr + e] = sqrtf(fmaxf(a * a + b * b + c * c, 1e-8f));
    }
}

// in-place sigmoid-norm gate on v[o][c*cs+e], rows of width MP
__device__ void gate_dev(float* vb, int nch, int MP, int cs, int tid)
{
    for (int idx = tid; idx < nch * cs; idx += NT) {
        int o = idx / cs, e = idx - o * cs;
        float* b = vb + o * MP + e;
        float a = b[0], b1 = b[cs], c = b[2 * cs];
        float n = sqrtf(fmaxf(a * a + b1 * b1 + c * c, 1e-8f));
        float g = 1.f / (1.f + expf(-n));
        b[0] = a * g; b[cs] = b1 * g; b[2 * cs] = c * g;
    }
}

// ---------------------------------------------------------------------------
// Edge kernel: one block per node; 30 edges (+2 zero pad) as GEMM M dimension.
// ---------------------------------------------------------------------------
__global__ __launch_bounds__(NT) void edge_kernel(P28 p)
{
    __shared__ __align__(16) float Bbuf[BBF];       // 12.8 KB weight chunks
    __shared__ __align__(16) float AM[165 * 32];    // 21.1 KB hM scalars(132)+vn1(33); later S2
    __shared__ __align__(16) float vhb[33 * 96];    // 12.7 KB vh / v ping-pong ([h][c*32+e])
    __shared__ __align__(16) float S1v[116 * 32];   // 14.8 KB vbuf alias -> sout1+vn2 -> sout3
    __shared__ __align__(16) float hVs[100];
    __shared__ float maskf[32];

    const int node = blockIdx.x;
    const int tid = threadIdx.x;
    const float* hV = p.h_V + (size_t)node * 148;
    float* vbuf = S1v;      // 33*96 = 3168 <= 3712
    float* S2 = AM;         // 116*32 = 3712 <= 5280

    for (int i = tid; i < 100; i += NT) hVs[i] = hV[48 + i];
    for (int i = tid; i < 32; i += NT)
        maskf[i] = (i < 30) ? (float)p.mask_attend[(size_t)node * 30 + i] : 0.f;
    // vbuf rows: i<16 = h_V vectors (replicated over e), i in [16,33) = h_M vectors
    for (int idx = tid; idx < 33 * 96; idx += NT) {
        int i = idx / 96, r = idx - i * 96, c = r >> 5, e = r & 31;
        float v = 0.f;
        if (i < 16) v = hV[c * 16 + i];
        else if (e < 30) v = p.h_M[((size_t)node * 30 + e) * 183 + c * 17 + (i - 16)];
        vbuf[idx] = v;
    }
    // AM rows 0..131: h_M scalars transposed [k][e]
    for (int idx = tid; idx < 132 * 32; idx += NT) {
        int k = idx >> 5, e = idx & 31;
        AM[idx] = (e < 30) ? p.h_M[((size_t)node * 30 + e) * 183 + 51 + k] : 0.f;
    }
    __syncthreads();

    // ---- GVP1 ----
    gemm(vbuf, 33, nullptr, 33, nullptr, 0, p.w1h, 33, 33, nullptr, false, vhb, 96, Bbuf, tid);
    __syncthreads();
    vn_dev(vhb, 33, 96, 32, AM + 132 * 32, 32, tid);                    // vn1 -> AM rows 132..164
    __syncthreads();
    gemm(AM, 165, nullptr, 165, hVs, 100, p.w1s, 100, 100, p.b1, true, S1v, 32, Bbuf, tid);
    gemm(vhb, 33, nullptr, 33, nullptr, 0, p.w1v, 16, 16, nullptr, false, vhb, 96, Bbuf, tid);
    __syncthreads();
    gate_dev(vhb, 16, 96, 32, tid);
    __syncthreads();

    // ---- GVP2 ----
    gemm(vhb, 16, nullptr, 16, nullptr, 0, p.w2h, 16, 16, nullptr, false, vhb + 16 * 96, 96, Bbuf, tid);
    __syncthreads();
    vn_dev(vhb + 16 * 96, 16, 96, 32, S1v + 100 * 32, 32, tid);         // vn2 -> S1 rows 100..115
    __syncthreads();
    gemm(S1v, 116, nullptr, 116, nullptr, 0, p.w2s, 100, 100, p.b2, true, S2, 32, Bbuf, tid);
    gemm(vhb + 16 * 96, 16, nullptr, 16, nullptr, 0, p.w2v, 16, 16, nullptr, false, vhb, 96, Bbuf, tid);
    __syncthreads();
    gate_dev(vhb, 16, 96, 32, tid);
    __syncthreads();

    // ---- GVP3 (no act) ----
    gemm(vhb, 16, nullptr, 16, nullptr, 0, p.w3h, 16, 16, nullptr, false, vhb + 16 * 96, 96, Bbuf, tid);
    __syncthreads();
    vn_dev(vhb + 16 * 96, 16, 96, 32, S2 + 100 * 32, 32, tid);          // vn3 -> S2 rows 100..115
    __syncthreads();
    gemm(S2, 116, nullptr, 116, nullptr, 0, p.w3s, 100, 100, p.b3, false, S1v, 32, Bbuf, tid);
    gemm(vhb + 16 * 96, 16, nullptr, 16, nullptr, 0, p.w3v, 16, 16, nullptr, false, vhb, 96, Bbuf, tid);
    __syncthreads();

    // ---- masked mean over 30 edges -> dh (staged in d_out) ----
    float* dhn = p.dh + (size_t)node * 148;
    for (int f = tid; f < 148; f += NT) {
        float s = 0.f;
        int e = f % 30;     // skew start to avoid bank-conflict lockstep
        if (f < 48) {
            int c = f >> 4, o = f & 15;
            const float* src = vhb + o * 96 + c * 32;
            for (int t = 0; t < 30; ++t) { s += maskf[e] * src[e]; if (++e == 30) e = 0; }
        } else {
            const float* src = S1v + (f - 48) * 32;
            for (int t = 0; t < 30; ++t) { s += maskf[e] * src[e]; if (++e == 30) e = 0; }
        }
        dhn[f] = s * (1.f / 30.f);
    }
}

// ---------------------------------------------------------------------------
// Node kernel: 16 nodes per block. LN1 -> W_dh (2 GVPs) -> LN2 -> mask.
// Reads dh from d_out (its own nodes only), then overwrites with final output.
// ---------------------------------------------------------------------------
__global__ __launch_bounds__(NT) void node_kernel(P28 p)
{
    __shared__ __align__(16) float Bbuf[BBF];
    __shared__ __align__(16) float S1n[132 * 16];   // LN1 scalars (0..99) + vn (100..131)
    __shared__ __align__(16) float A2n[400 * 16];   // sout1 (relu'd)
    __shared__ __align__(16) float s2n[100 * 16];   // sout2
    __shared__ __align__(16) float hvv[16 * 48];    // LN1 vectors [i][c*16+n]
    __shared__ __align__(16) float vhA[32 * 48];
    __shared__ __align__(16) float vhB[32 * 48];
    __shared__ float mu[16], isd[16], vrm[16], mkv[16];

    const int nb = blockIdx.x * 16;
    const int tid = threadIdx.x;

    // stage x = h_V + dh
    for (int idx = tid; idx < 1600; idx += NT) {
        int n = idx & 15, j = idx >> 4;
        size_t g = (size_t)(nb + n) * 148 + 48 + j;
        S1n[idx] = p.h_V[g] + p.dh[g];
    }
    for (int idx = tid; idx < 768; idx += NT) {
        int i = idx / 48, r = idx - i * 48, c = r >> 4, n = r & 15;
        size_t g = (size_t)(nb + n) * 148 + c * 16 + i;
        hvv[idx] = p.h_V[g] + p.dh[g];
    }
    for (int i = tid; i < 16; i += NT) mkv[i] = (float)p.mask_V[nb + i];
    __syncthreads();

    // LN1 stats (one thread per node)
    if (tid < 16) {
        int n = tid;
        float sm = 0.f;
        for (int j = 0; j < 100; ++j) sm += S1n[j * 16 + n];
        float m = sm * 0.01f, var = 0.f;
        for (int j = 0; j < 100; ++j) { float d = S1n[j * 16 + n] - m; var += d * d; }
        mu[n] = m; isd[n] = rsqrtf(var * 0.01f + 1e-3f);
        float vm = 0.f;
        for (int i = 0; i < 16; ++i) {
            float a = hvv[i * 48 + n], b = hvv[i * 48 + 16 + n], c = hvv[i * 48 + 32 + n];
            vm += fmaxf(a * a + b * b + c * c, 1e-8f);
        }
        vrm[n] = rsqrtf(vm * (1.f / 16.f));
    }
    __syncthreads();
    for (int idx = tid; idx < 1600; idx += NT) {
        int n = idx & 15, j = idx >> 4;
        S1n[idx] = (S1n[idx] - mu[n]) * isd[n] * p.g1[j] + p.be1[j];
    }
    for (int idx = tid; idx < 768; idx += NT) hvv[idx] *= vrm[idx & 15];
    __syncthreads();

    // ---- W_dh GVP1: 16v->32v, 132s->400s (act) ----
    gemm(hvv, 16, nullptr, 16, nullptr, 0, p.d1h, 32, 32, nullptr, false, vhA, 48, Bbuf, tid);
    __syncthreads();
    vn_dev(vhA, 32, 48, 16, S1n + 100 * 16, 16, tid);                   // vn1 -> S1n rows 100..131
    __syncthreads();
    gemm(S1n, 132, nullptr, 132, nullptr, 0, p.d1s,       400, 200, p.db1,       true, A2n,            16, Bbuf, tid);
    gemm(S1n, 132, nullptr, 132, nullptr, 0, p.d1s + 200, 400, 200, p.db1 + 200, true, A2n + 200 * 16, 16, Bbuf, tid);
    gemm(vhA, 32, nullptr, 32, nullptr, 0, p.d1v, 32, 32, nullptr, false, vhB, 48, Bbuf, tid);
    __syncthreads();
    gate_dev(vhB, 32, 48, 16, tid);
    __syncthreads();

    // ---- W_dh GVP2: 32v->16v, 432s->100s (no act) ----
    gemm(vhB, 32, nullptr, 32, nullptr, 0, p.d2h, 32, 32, nullptr, false, vhA, 48, Bbuf, tid);
    __syncthreads();
    vn_dev(vhA, 32, 48, 16, S1n + 100 * 16, 16, tid);                   // vn2 overwrites rows 100..131
    __syncthreads();
    gemm(A2n, 400, S1n + 100 * 16, 432, nullptr, 0, p.d2s, 100, 100, p.db2, false, s2n, 16, Bbuf, tid);
    gemm(vhA, 32, nullptr, 32, nullptr, 0, p.d2v, 16, 16, nullptr, false, vhB, 48, Bbuf, tid);
    __syncthreads();

    // residual: x2 = hv + dh2
    for (int idx = tid; idx < 1600; idx += NT) s2n[idx] += S1n[idx];
    for (int idx = tid; idx < 768; idx += NT) vhB[idx] += hvv[idx];
    __syncthreads();

    // LN2 stats
    if (tid < 16) {
        int n = tid;
        float sm = 0.f;
        for (int j = 0; j < 100; ++j) sm += s2n[j * 16 + n];
        float m = sm * 0.01f, var = 0.f;
        for (int j = 0; j < 100; ++j) { float d = s2n[j * 16 + n] - m; var += d * d; }
        mu[n] = m; isd[n] = rsqrtf(var * 0.01f + 1e-3f);
        float vm = 0.f;
        for (int i = 0; i < 16; ++i) {
            float a = vhB[i * 48 + n], b = vhB[i * 48 + 16 + n], c = vhB[i * 48 + 32 + n];
            vm += fmaxf(a * a + b * b + c * c, 1e-8f);
        }
        vrm[n] = rsqrtf(vm * (1.f / 16.f));
    }
    __syncthreads();
    for (int idx = tid; idx < 1600; idx += NT) {
        int n = idx & 15, j = idx >> 4;
        s2n[idx] = (s2n[idx] - mu[n]) * isd[n] * p.g2[j] + p.be2[j];
    }
    for (int idx = tid; idx < 768; idx += NT) vhB[idx] *= vrm[idx & 15];
    __syncthreads();

    // write out = mask_V * hv2 (coalesced over f)
    for (int idx = tid; idx < 16 * 148; idx += NT) {
        int n = idx / 148, f = idx - n * 148;
        float v;
        if (f < 48) { int c = f >> 4, o = f & 15; v = vhB[o * 48 + c * 16 + n]; }
        else        { v = s2n[(f - 48) * 16 + n]; }
        p.out[(size_t)(nb + n) * 148 + f] = mkv[n] * v;
    }
}

extern "C" void kernel_launch(void* const* d_in, const int* in_sizes, int n_in,
                              void* d_out, int out_size, void* d_ws, size_t ws_size,
                              hipStream_t stream)
{
    P28 p;
    p.h_V = (const float*)d_in[0];
    p.h_M = (const float*)d_in[1];
    p.mask_V = (const int*)d_in[2];
    p.mask_attend = (const int*)d_in[3];
    const float** w = (const float**)&p.w1h;
    for (int i = 0; i < 24; ++i) w[i] = (const float*)d_in[4 + i];
    p.out = (float*)d_out;
    p.dh  = (float*)d_out;   // stage dh in d_out; node kernel reads then overwrites

    edge_kernel<<<dim3(8192), dim3(NT), 0, stream>>>(p);
    node_kernel<<<dim3(512),  dim3(NT), 0, stream>>>(p);
}

// Round 5
// 971.910 us; speedup vs baseline: 54.5832x; 1.1143x over previous
//
#include <hip/hip_runtime.h>
#include <math.h>

#define NT 256

typedef __attribute__((ext_vector_type(8))) short short8;
typedef __attribute__((ext_vector_type(4))) float float4v;

struct P28 {
    const float *h_V, *h_M;
    const int *mask_V, *mask_attend;
    const float *w1h,*w1s,*b1,*w1v;
    const float *w2h,*w2s,*b2,*w2v;
    const float *w3h,*w3s,*b3,*w3v;
    const float *d1h,*d1s,*db1,*d1v;
    const float *d2h,*d2s,*db2,*d2v;
    const float *g1,*be1,*g2,*be2;
    float *out, *dh;
    short *wt1, *wt2, *wt3;   // bf16 [n][Kpad] weight layouts in d_ws
};

__device__ inline short f2bf(float f) {
    union { float f; unsigned u; } v; v.f = f;
    unsigned r = (v.u + 0x7FFFu + ((v.u >> 16) & 1u)) >> 16;   // RNE
    return (short)r;
}

// ---------------------------------------------------------------------------
// fp32 tiled GEMM (VALU) — used for the small vector-path matmuls and the
// node kernel. LDS A, global B streamed through Bbuf (float4 prefetch).
// out[j*MP+m]; one thread = 4x4 tile. Requires (MP/4)*((N+3)/4) <= NT.
// Final __syncthreads() precedes stores, so outL may alias A0/A1.
// ---------------------------------------------------------------------------
__device__ void gemm(const float* A0, int split, const float* A1, int KA,
                     const float* uni, int uniK,
                     const float* Bg, int ldB, int N,
                     const float* bias, bool relu,
                     float* outL, int MP, float* Bbuf, int bbf, int tid)
{
    const bool vec = ((N & 3) == 0) && ((ldB & 3) == 0);
    const int Npad = vec ? N : ((N + 3) & ~3);
    const int EQ = MP >> 2;
    const int npairs = EQ * (Npad >> 2);
    const int Ktot = uniK + KA;
    int KC = bbf / Npad;
    if (KC > Ktot) KC = Ktot;

    const bool active = tid < npairs;
    const int e0 = (active ? (tid % EQ) : 0) * 4;
    const int j0 = (active ? (tid / EQ) : 0) * 4;

    float c00=0.f,c01=0.f,c02=0.f,c03=0.f;
    float c10=0.f,c11=0.f,c12=0.f,c13=0.f;
    float c20=0.f,c21=0.f,c22=0.f,c23=0.f;
    float c30=0.f,c31=0.f,c32=0.f,c33=0.f;
    float su0=0.f,su1=0.f,su2=0.f,su3=0.f;

    float4 r0, r1, r2, r3;
    r0.x=r0.y=r0.z=r0.w=0.f; r1=r0; r2=r0; r3=r0;

    if (vec) {
        int kc0 = (KC < Ktot) ? KC : Ktot;
        int nf4 = (kc0 * N) >> 2;
        int f4 = tid;
        if (f4 < nf4) { int f = f4*4; int k = f / N; r0 = *(const float4*)(Bg + (size_t)k*ldB + (f - k*N)); }
        f4 = tid + NT;
        if (f4 < nf4) { int f = f4*4; int k = f / N; r1 = *(const float4*)(Bg + (size_t)k*ldB + (f - k*N)); }
        f4 = tid + 2*NT;
        if (f4 < nf4) { int f = f4*4; int k = f / N; r2 = *(const float4*)(Bg + (size_t)k*ldB + (f - k*N)); }
        f4 = tid + 3*NT;
        if (f4 < nf4) { int f = f4*4; int k = f / N; r3 = *(const float4*)(Bg + (size_t)k*ldB + (f - k*N)); }
    }

    for (int k0 = 0; k0 < Ktot; k0 += KC) {
        int kc = Ktot - k0; if (kc > KC) kc = KC;
        __syncthreads();
        if (vec) {
            int nf4 = (kc * N) >> 2;
            float4* Bb4 = (float4*)Bbuf;
            if (tid        < nf4) Bb4[tid]        = r0;
            if (tid +   NT < nf4) Bb4[tid +   NT] = r1;
            if (tid + 2*NT < nf4) Bb4[tid + 2*NT] = r2;
            if (tid + 3*NT < nf4) Bb4[tid + 3*NT] = r3;
            int k0n = k0 + KC;
            if (k0n < Ktot) {
                int kcn = Ktot - k0n; if (kcn > KC) kcn = KC;
                int nf4n = (kcn * N) >> 2;
                const float* Bn = Bg + (size_t)k0n * ldB;
                int f4 = tid;
                if (f4 < nf4n) { int f = f4*4; int k = f / N; r0 = *(const float4*)(Bn + (size_t)k*ldB + (f - k*N)); }
                f4 = tid + NT;
                if (f4 < nf4n) { int f = f4*4; int k = f / N; r1 = *(const float4*)(Bn + (size_t)k*ldB + (f - k*N)); }
                f4 = tid + 2*NT;
                if (f4 < nf4n) { int f = f4*4; int k = f / N; r2 = *(const float4*)(Bn + (size_t)k*ldB + (f - k*N)); }
                f4 = tid + 3*NT;
                if (f4 < nf4n) { int f = f4*4; int k = f / N; r3 = *(const float4*)(Bn + (size_t)k*ldB + (f - k*N)); }
            }
        } else {
            for (int idx = tid; idx < kc * Npad; idx += NT) {
                int k = idx / Npad, j = idx - k * Npad;
                Bbuf[idx] = (j < N) ? Bg[(size_t)(k0 + k) * ldB + j] : 0.f;
            }
        }
        __syncthreads();
        if (active) {
            for (int k = 0; k < kc; ++k) {
                int kg = k0 + k;
                float4 b4 = *(const float4*)(Bbuf + k * Npad + j0);
                if (kg < uniK) {
                    float u = uni[kg];
                    su0 = fmaf(u, b4.x, su0); su1 = fmaf(u, b4.y, su1);
                    su2 = fmaf(u, b4.z, su2); su3 = fmaf(u, b4.w, su3);
                } else {
                    int ka = kg - uniK;
                    const float* arow = (ka < split) ? (A0 + (size_t)ka * MP + e0)
                                                     : (A1 + (size_t)(ka - split) * MP + e0);
                    float4 a4 = *(const float4*)arow;
                    c00 = fmaf(a4.x, b4.x, c00); c01 = fmaf(a4.y, b4.x, c01);
                    c02 = fmaf(a4.z, b4.x, c02); c03 = fmaf(a4.w, b4.x, c03);
                    c10 = fmaf(a4.x, b4.y, c10); c11 = fmaf(a4.y, b4.y, c11);
                    c12 = fmaf(a4.z, b4.y, c12); c13 = fmaf(a4.w, b4.y, c13);
                    c20 = fmaf(a4.x, b4.z, c20); c21 = fmaf(a4.y, b4.z, c21);
                    c22 = fmaf(a4.z, b4.z, c22); c23 = fmaf(a4.w, b4.z, c23);
                    c30 = fmaf(a4.x, b4.w, c30); c31 = fmaf(a4.y, b4.w, c31);
                    c32 = fmaf(a4.z, b4.w, c32); c33 = fmaf(a4.w, b4.w, c33);
                }
            }
        }
    }
    __syncthreads();
    if (active) {
        float4 o;
        if (j0 + 0 < N) {
            float s = su0 + (bias ? bias[j0 + 0] : 0.f);
            o.x = c00 + s; o.y = c01 + s; o.z = c02 + s; o.w = c03 + s;
            if (relu) { o.x = fmaxf(o.x,0.f); o.y = fmaxf(o.y,0.f); o.z = fmaxf(o.z,0.f); o.w = fmaxf(o.w,0.f); }
            *(float4*)(outL + (size_t)(j0 + 0) * MP + e0) = o;
        }
        if (j0 + 1 < N) {
            float s = su1 + (bias ? bias[j0 + 1] : 0.f);
            o.x = c10 + s; o.y = c11 + s; o.z = c12 + s; o.w = c13 + s;
            if (relu) { o.x = fmaxf(o.x,0.f); o.y = fmaxf(o.y,0.f); o.z = fmaxf(o.z,0.f); o.w = fmaxf(o.w,0.f); }
            *(float4*)(outL + (size_t)(j0 + 1) * MP + e0) = o;
        }
        if (j0 + 2 < N) {
            float s = su2 + (bias ? bias[j0 + 2] : 0.f);
            o.x = c20 + s; o.y = c21 + s; o.z = c22 + s; o.w = c23 + s;
            if (relu) { o.x = fmaxf(o.x,0.f); o.y = fmaxf(o.y,0.f); o.z = fmaxf(o.z,0.f); o.w = fmaxf(o.w,0.f); }
            *(float4*)(outL + (size_t)(j0 + 2) * MP + e0) = o;
        }
        if (j0 + 3 < N) {
            float s = su3 + (bias ? bias[j0 + 3] : 0.f);
            o.x = c30 + s; o.y = c31 + s; o.z = c32 + s; o.w = c33 + s;
            if (relu) { o.x = fmaxf(o.x,0.f); o.y = fmaxf(o.y,0.f); o.z = fmaxf(o.z,0.f); o.w = fmaxf(o.w,0.f); }
            *(float4*)(outL + (size_t)(j0 + 3) * MP + e0) = o;
        }
    }
}

__device__ void vn_dev(const float* vh, int nch, int MP, int cs,
                       float* out, int ostr, int tid)
{
    for (int idx = tid; idx < nch * cs; idx += NT) {
        int h = idx / cs, e = idx - h * cs;
        float a = vh[h * MP + e], b = vh[h * MP + cs + e], c = vh[h * MP + 2 * cs + e];
        out[h * ostr + e] = sqrtf(fmaxf(a * a + b * b + c * c, 1e-8f));
    }
}

__device__ void gate_dev(float* vb, int nch, int MP, int cs, int tid)
{
    for (int idx = tid; idx < nch * cs; idx += NT) {
        int o = idx / cs, e = idx - o * cs;
        float* b = vb + o * MP + e;
        float a = b[0], b1 = b[cs], c = b[2 * cs];
        float n = sqrtf(fmaxf(a * a + b1 * b1 + c * c, 1e-8f));
        float g = 1.f / (1.f + expf(-n));
        b[0] = a * g; b[cs] = b1 * g; b[2 * cs] = c * g;
    }
}

// ---------------------------------------------------------------------------
// MFMA GEMM: M=32 edges, N=100 (7 n-tiles of 16, cols>=100 discarded),
// A bf16 LDS [32][Astr], B bf16 GLOBAL [112][Kpad] ([n][k], prep-transposed).
// 14 tiles distributed over 4 waves. Verified layouts (m89/m120):
//   a_frag: A[m=lane&15][k=(lane>>4)*8+j]   b_frag: B[k=(lane>>4)*8+j][n=lane&15]
//   D:      row=(lane>>4)*4+r, col=lane&15
// outA: relu+bf16 -> [e][outAstr] ; outS: fp32 -> [j][33].
// ---------------------------------------------------------------------------
__device__ void mfma_gemm(const short* Alds, int Astr, const short* Bg, int Kpad,
                          int ktiles, const float* bias,
                          short* outA, int outAstr, float* outS, int tid)
{
    const int w = tid >> 6, lane = tid & 63;
    const int q = lane >> 4, l16 = lane & 15;
    for (int t = w; t < 14; t += 4) {
        int mt = t & 1, nt = t >> 1;
        const short* ap = Alds + (mt * 16 + l16) * Astr + q * 8;
        const short* bp = Bg + (size_t)(nt * 16 + l16) * Kpad + q * 8;
        float4v acc = {0.f, 0.f, 0.f, 0.f};
        for (int kt = 0; kt < ktiles; ++kt) {
            short8 a = *(const short8*)(ap + kt * 32);
            short8 b = *(const short8*)(bp + kt * 32);
            acc = __builtin_amdgcn_mfma_f32_16x16x32_bf16(a, b, acc, 0, 0, 0);
        }
        int j = nt * 16 + l16;
        if (j < 100) {
            float bj = bias ? bias[j] : 0.f;
            int ebase = mt * 16 + q * 4;
            for (int r = 0; r < 4; ++r) {
                float v = acc[r] + bj;
                if (outA) { v = fmaxf(v, 0.f); outA[(ebase + r) * outAstr + j] = f2bf(v); }
                else      { outS[j * 33 + (ebase + r)] = v; }
            }
        }
    }
}

// ---------------------------------------------------------------------------
// prep: transpose+convert the three s-path weight matrices to bf16 [n][Kpad].
// wt1 [112][288]: A1 col order = 132 hM_s (ws rows 100..231), 33 vn (232..264),
//                 100 hV_s (0..99), zero pad.
// wt2/wt3 [112][128]: w_s rows 0..115 direct.
// ---------------------------------------------------------------------------
__global__ __launch_bounds__(NT) void prep_w(P28 p)
{
    int id = blockIdx.x * NT + threadIdx.x;
    int stride = gridDim.x * NT;
    for (int i = id; i < 112 * 288; i += stride) {
        int n = i / 288, k = i - n * 288;
        float v = 0.f;
        if (n < 100) {
            int row = -1;
            if (k < 132) row = 100 + k;
            else if (k < 165) row = 232 + (k - 132);
            else if (k < 265) row = k - 165;
            if (row >= 0) v = p.w1s[(size_t)row * 100 + n];
        }
        p.wt1[i] = f2bf(v);
    }
    for (int i = id; i < 112 * 128; i += stride) {
        int n = i / 128, k = i - n * 128;
        p.wt2[i] = f2bf((n < 100 && k < 116) ? p.w2s[(size_t)k * 100 + n] : 0.f);
    }
    for (int i = id; i < 112 * 128; i += stride) {
        int n = i / 128, k = i - n * 128;
        p.wt3[i] = f2bf((n < 100 && k < 116) ? p.w3s[(size_t)k * 100 + n] : 0.f);
    }
}

// ---------------------------------------------------------------------------
// Edge kernel: one block per node; 30 edges (+2 pad). s-path on MFMA.
// ---------------------------------------------------------------------------
__global__ __launch_bounds__(NT) void edge_kernel(P28 p)
{
    __shared__ __align__(16) float Bbuf[1200];        //  4.8 KB (v-path weights)
    __shared__ __align__(16) short A1s[32 * 296];     // 18.9 KB GEMM1 A (bf16); aliased by A3
    __shared__ __align__(16) float bufY[3300];        // 13.2 KB vbuf -> A2 (bf16) -> S3 (fp32)
    __shared__ __align__(16) float vhb[33 * 96];      // 12.7 KB v-path fp32 ping-pong
    __shared__ float maskf[32];

    short* A3s = A1s;                 // 32*136 sh = 8.7 KB <= A1s
    short* A2s = (short*)bufY;        // 32*136 sh = 8.7 KB <= bufY
    float* vbuf = bufY;               // 33*96 f = 12.7 KB
    float* S3   = bufY;               // 100*33 f = 13.2 KB

    const int node = blockIdx.x, tid = threadIdx.x;
    const float* hV = p.h_V + (size_t)node * 148;

    for (int i = tid; i < 32; i += NT)
        maskf[i] = (i < 30) ? (float)p.mask_attend[(size_t)node * 30 + i] : 0.f;
    // A1 cols 0..131: hM scalars bf16 (coalesced over k within an e-row)
    for (int idx = tid; idx < 32 * 132; idx += NT) {
        int e = idx / 132, k = idx - e * 132;
        float v = (e < 30) ? p.h_M[((size_t)node * 30 + e) * 183 + 51 + k] : 0.f;
        A1s[e * 296 + k] = f2bf(v);
    }
    // A1 cols 165..264: hV scalars replicated over e
    for (int idx = tid; idx < 32 * 100; idx += NT) {
        int i = idx >> 5, e = idx & 31;
        A1s[e * 296 + 165 + i] = f2bf(hV[48 + i]);
    }
    // A1 cols 265..287: zero (K pad)
    for (int idx = tid; idx < 32 * 23; idx += NT) {
        int kk = idx / 32, e = idx - kk * 32;
        A1s[e * 296 + 265 + kk] = 0;
    }
    // vbuf fp32 vectors [i][c*32+e]: rows 0..15 hV (replicated), 16..32 hM
    for (int idx = tid; idx < 33 * 96; idx += NT) {
        int i = idx / 96, r = idx - i * 96, c = r >> 5, e = r & 31;
        float v = 0.f;
        if (i < 16) v = hV[c * 16 + i];
        else if (e < 30) v = p.h_M[((size_t)node * 30 + e) * 183 + c * 17 + (i - 16)];
        vbuf[idx] = v;
    }
    __syncthreads();

    // ---- GVP1 v-path: vh1 = vbuf @ w1h ----
    gemm(vbuf, 33, nullptr, 33, nullptr, 0, p.w1h, 33, 33, nullptr, false, vhb, 96, Bbuf, 1200, tid);
    __syncthreads();
    // vn1 -> A1 cols 132..164 (bf16); zero A2 pad cols 116..127 (vbuf now dead)
    for (int idx = tid; idx < 33 * 32; idx += NT) {
        int h = idx >> 5, e = idx & 31;
        float a = vhb[h * 96 + e], b = vhb[h * 96 + 32 + e], c = vhb[h * 96 + 64 + e];
        A1s[e * 296 + 132 + h] = f2bf(sqrtf(fmaxf(a * a + b * b + c * c, 1e-8f)));
    }
    for (int idx = tid; idx < 32 * 12; idx += NT) {
        int kk = idx >> 5, e = idx & 31;
        A2s[e * 136 + 116 + kk] = 0;
    }
    __syncthreads();
    // v1 = gate(vh1 @ w1v)
    gemm(vhb, 33, nullptr, 33, nullptr, 0, p.w1v, 16, 16, nullptr, false, vhb, 96, Bbuf, 1200, tid);
    __syncthreads();
    gate_dev(vhb, 16, 96, 32, tid);
    __syncthreads();
    // ---- MFMA GEMM1: s1 = relu(A1 @ wt1 + b1) -> A2 bf16 ----
    mfma_gemm(A1s, 296, p.wt1, 288, 9, p.b1, A2s, 136, nullptr, tid);
    __syncthreads();

    // ---- GVP2 v-path ----
    gemm(vhb, 16, nullptr, 16, nullptr, 0, p.w2h, 16, 16, nullptr, false, vhb + 16 * 96, 96, Bbuf, 1200, tid);
    __syncthreads();
    // vn2 -> A2 cols 100..115; zero A3 pad cols (A1 dead after GEMM1)
    for (int idx = tid; idx < 16 * 32; idx += NT) {
        int h = idx >> 5, e = idx & 31;
        float a = vhb[(16 + h) * 96 + e], b = vhb[(16 + h) * 96 + 32 + e], c = vhb[(16 + h) * 96 + 64 + e];
        A2s[e * 136 + 100 + h] = f2bf(sqrtf(fmaxf(a * a + b * b + c * c, 1e-8f)));
    }
    for (int idx = tid; idx < 32 * 12; idx += NT) {
        int kk = idx >> 5, e = idx & 31;
        A3s[e * 136 + 116 + kk] = 0;
    }
    __syncthreads();
    gemm(vhb + 16 * 96, 16, nullptr, 16, nullptr, 0, p.w2v, 16, 16, nullptr, false, vhb, 96, Bbuf, 1200, tid);
    __syncthreads();
    gate_dev(vhb, 16, 96, 32, tid);
    __syncthreads();
    // ---- MFMA GEMM2: s2 = relu(A2 @ wt2 + b2) -> A3 bf16 ----
    mfma_gemm(A2s, 136, p.wt2, 128, 4, p.b2, A3s, 136, nullptr, tid);
    __syncthreads();

    // ---- GVP3 v-path (no gate) ----
    gemm(vhb, 16, nullptr, 16, nullptr, 0, p.w3h, 16, 16, nullptr, false, vhb + 16 * 96, 96, Bbuf, 1200, tid);
    __syncthreads();
    for (int idx = tid; idx < 16 * 32; idx += NT) {
        int h = idx >> 5, e = idx & 31;
        float a = vhb[(16 + h) * 96 + e], b = vhb[(16 + h) * 96 + 32 + e], c = vhb[(16 + h) * 96 + 64 + e];
        A3s[e * 136 + 100 + h] = f2bf(sqrtf(fmaxf(a * a + b * b + c * c, 1e-8f)));
    }
    __syncthreads();
    gemm(vhb + 16 * 96, 16, nullptr, 16, nullptr, 0, p.w3v, 16, 16, nullptr, false, vhb, 96, Bbuf, 1200, tid);
    __syncthreads();
    // ---- MFMA GEMM3: s3 = A3 @ wt3 + b3 -> S3 fp32 [j][33] (A2 dead) ----
    mfma_gemm(A3s, 136, p.wt3, 128, 4, p.b3, nullptr, 0, S3, tid);
    __syncthreads();

    // ---- masked mean over 30 edges -> dh (staged in d_out) ----
    float* dhn = p.dh + (size_t)node * 148;
    for (int f = tid; f < 148; f += NT) {
        float s = 0.f;
        int e = f % 30;
        if (f < 48) {
            int c = f >> 4, o = f & 15;
            const float* src = vhb + o * 96 + c * 32;
            for (int t = 0; t < 30; ++t) { s += maskf[e] * src[e]; if (++e == 30) e = 0; }
        } else {
            const float* src = S3 + (size_t)(f - 48) * 33;
            for (int t = 0; t < 30; ++t) { s += maskf[e] * src[e]; if (++e == 30) e = 0; }
        }
        dhn[f] = s * (1.f / 30.f);
    }
}

// ---------------------------------------------------------------------------
// Node kernel: 16 nodes per block. LN1 -> W_dh (2 GVPs) -> LN2 -> mask.
// Reads dh from d_out (its own nodes only), then overwrites with final output.
// ---------------------------------------------------------------------------
__global__ __launch_bounds__(NT) void node_kernel(P28 p)
{
    __shared__ __align__(16) float Bbuf[3200];
    __shared__ __align__(16) float S1n[132 * 16];
    __shared__ __align__(16) float A2n[400 * 16];
    __shared__ __align__(16) float s2n[100 * 16];
    __shared__ __align__(16) float hvv[16 * 48];
    __shared__ __align__(16) float vhA[32 * 48];
    __shared__ __align__(16) float vhB[32 * 48];
    __shared__ float mu[16], isd[16], vrm[16], mkv[16];

    const int nb = blockIdx.x * 16;
    const int tid = threadIdx.x;

    for (int idx = tid; idx < 1600; idx += NT) {
        int n = idx & 15, j = idx >> 4;
        size_t g = (size_t)(nb + n) * 148 + 48 + j;
        S1n[idx] = p.h_V[g] + p.dh[g];
    }
    for (int idx = tid; idx < 768; idx += NT) {
        int i = idx / 48, r = idx - i * 48, c = r >> 4, n = r & 15;
        size_t g = (size_t)(nb + n) * 148 + c * 16 + i;
        hvv[idx] = p.h_V[g] + p.dh[g];
    }
    for (int i = tid; i < 16; i += NT) mkv[i] = (float)p.mask_V[nb + i];
    __syncthreads();

    if (tid < 16) {
        int n = tid;
        float sm = 0.f;
        for (int j = 0; j < 100; ++j) sm += S1n[j * 16 + n];
        float m = sm * 0.01f, var = 0.f;
        for (int j = 0; j < 100; ++j) { float d = S1n[j * 16 + n] - m; var += d * d; }
        mu[n] = m; isd[n] = rsqrtf(var * 0.01f + 1e-3f);
        float vm = 0.f;
        for (int i = 0; i < 16; ++i) {
            float a = hvv[i * 48 + n], b = hvv[i * 48 + 16 + n], c = hvv[i * 48 + 32 + n];
            vm += fmaxf(a * a + b * b + c * c, 1e-8f);
        }
        vrm[n] = rsqrtf(vm * (1.f / 16.f));
    }
    __syncthreads();
    for (int idx = tid; idx < 1600; idx += NT) {
        int n = idx & 15, j = idx >> 4;
        S1n[idx] = (S1n[idx] - mu[n]) * isd[n] * p.g1[j] + p.be1[j];
    }
    for (int idx = tid; idx < 768; idx += NT) hvv[idx] *= vrm[idx & 15];
    __syncthreads();

    gemm(hvv, 16, nullptr, 16, nullptr, 0, p.d1h, 32, 32, nullptr, false, vhA, 48, Bbuf, 3200, tid);
    __syncthreads();
    vn_dev(vhA, 32, 48, 16, S1n + 100 * 16, 16, tid);
    __syncthreads();
    gemm(S1n, 132, nullptr, 132, nullptr, 0, p.d1s,       400, 200, p.db1,       true, A2n,            16, Bbuf, 3200, tid);
    gemm(S1n, 132, nullptr, 132, nullptr, 0, p.d1s + 200, 400, 200, p.db1 + 200, true, A2n + 200 * 16, 16, Bbuf, 3200, tid);
    gemm(vhA, 32, nullptr, 32, nullptr, 0, p.d1v, 32, 32, nullptr, false, vhB, 48, Bbuf, 3200, tid);
    __syncthreads();
    gate_dev(vhB, 32, 48, 16, tid);
    __syncthreads();

    gemm(vhB, 32, nullptr, 32, nullptr, 0, p.d2h, 32, 32, nullptr, false, vhA, 48, Bbuf, 3200, tid);
    __syncthreads();
    vn_dev(vhA, 32, 48, 16, S1n + 100 * 16, 16, tid);
    __syncthreads();
    gemm(A2n, 400, S1n + 100 * 16, 432, nullptr, 0, p.d2s, 100, 100, p.db2, false, s2n, 16, Bbuf, 3200, tid);
    gemm(vhA, 32, nullptr, 32, nullptr, 0, p.d2v, 16, 16, nullptr, false, vhB, 48, Bbuf, 3200, tid);
    __syncthreads();

    for (int idx = tid; idx < 1600; idx += NT) s2n[idx] += S1n[idx];
    for (int idx = tid; idx < 768; idx += NT) vhB[idx] += hvv[idx];
    __syncthreads();

    if (tid < 16) {
        int n = tid;
        float sm = 0.f;
        for (int j = 0; j < 100; ++j) sm += s2n[j * 16 + n];
        float m = sm * 0.01f, var = 0.f;
        for (int j = 0; j < 100; ++j) { float d = s2n[j * 16 + n] - m; var += d * d; }
        mu[n] = m; isd[n] = rsqrtf(var * 0.01f + 1e-3f);
        float vm = 0.f;
        for (int i = 0; i < 16; ++i) {
            float a = vhB[i * 48 + n], b = vhB[i * 48 + 16 + n], c = vhB[i * 48 + 32 + n];
            vm += fmaxf(a * a + b * b + c * c, 1e-8f);
        }
        vrm[n] = rsqrtf(vm * (1.f / 16.f));
    }
    __syncthreads();
    for (int idx = tid; idx < 1600; idx += NT) {
        int n = idx & 15, j = idx >> 4;
        s2n[idx] = (s2n[idx] - mu[n]) * isd[n] * p.g2[j] + p.be2[j];
    }
    for (int idx = tid; idx < 768; idx += NT) vhB[idx] *= vrm[idx & 15];
    __syncthreads();

    for (int idx = tid; idx < 16 * 148; idx += NT) {
        int n = idx / 148, f = idx - n * 148;
        float v;
        if (f < 48) { int c = f >> 4, o = f & 15; v = vhB[o * 48 + c * 16 + n]; }
        else        { v = s2n[(f - 48) * 16 + n]; }
        p.out[(size_t)(nb + n) * 148 + f] = mkv[n] * v;
    }
}

extern "C" void kernel_launch(void* const* d_in, const int* in_sizes, int n_in,
                              void* d_out, int out_size, void* d_ws, size_t ws_size,
                              hipStream_t stream)
{
    P28 p;
    p.h_V = (const float*)d_in[0];
    p.h_M = (const float*)d_in[1];
    p.mask_V = (const int*)d_in[2];
    p.mask_attend = (const int*)d_in[3];
    const float** w = (const float**)&p.w1h;
    for (int i = 0; i < 24; ++i) w[i] = (const float*)d_in[4 + i];
    p.out = (float*)d_out;
    p.dh  = (float*)d_out;              // stage dh in d_out; node kernel reads then overwrites
    p.wt1 = (short*)d_ws;               // 112*288 bf16
    p.wt2 = p.wt1 + 112 * 288;          // 112*128 bf16
    p.wt3 = p.wt2 + 112 * 128;          // 112*128 bf16

    prep_w<<<dim3(64), dim3(NT), 0, stream>>>(p);
    edge_kernel<<<dim3(8192), dim3(NT), 0, stream>>>(p);
    node_kernel<<<dim3(512),  dim3(NT), 0, stream>>>(p);
}